// Round 13
// baseline (194.025 us; speedup 1.0000x reference)
//
#include <hip/hip_runtime.h>

typedef float f32x4 __attribute__((ext_vector_type(4)));
typedef __bf16 bf16x8 __attribute__((ext_vector_type(8)));
typedef unsigned short u16;
typedef unsigned int u32;
typedef u16 u16x4 __attribute__((ext_vector_type(4)));
typedef u16 u16x8 __attribute__((ext_vector_type(8)));
typedef u32 u32x2 __attribute__((ext_vector_type(2)));
typedef u32 u32x4 __attribute__((ext_vector_type(4)));

constexpr int Bn = 4, Sn = 2048, Dn = 1024, Hn = 16, DHn = 64;
constexpr int Mn = Bn * Sn; // 8192

static __device__ __forceinline__ u16 f2bf(float f) {
  return __builtin_bit_cast(u16, (__bf16)f);
}

static __device__ __forceinline__ u32 cvtpk(float lo, float hi) {
  u32 r;
  asm("v_cvt_pk_bf16_f32 %0, %1, %2" : "=v"(r) : "v"(lo), "v"(hi));
  return r;
}

// async global->LDS, 16B per lane. LDS dest is wave-uniform base + lane*16.
static __device__ __forceinline__ void async16(const void* g, void* l) {
  __builtin_amdgcn_global_load_lds((const __attribute__((address_space(1))) u32*)g,
                                   (__attribute__((address_space(3))) u32*)l, 16, 0, 0);
}

// counted vmcnt wait + raw barrier, fenced (guide rule #18)
static __device__ __forceinline__ void wait_bar2() {
  asm volatile("s_waitcnt vmcnt(2)" ::: "memory");
  __builtin_amdgcn_sched_barrier(0);
  __builtin_amdgcn_s_barrier();
  __builtin_amdgcn_sched_barrier(0);
}
static __device__ __forceinline__ void wait_bar8() {
  asm volatile("s_waitcnt vmcnt(8)" ::: "memory");
  __builtin_amdgcn_sched_barrier(0);
  __builtin_amdgcn_s_barrier();
  __builtin_amdgcn_sched_barrier(0);
}
static __device__ __forceinline__ void wait_bar0() {
  asm volatile("s_waitcnt vmcnt(0)" ::: "memory");
  __builtin_amdgcn_sched_barrier(0);
  __builtin_amdgcn_s_barrier();
  __builtin_amdgcn_sched_barrier(0);
}
static __device__ __forceinline__ void raw_bar() {
  __builtin_amdgcn_sched_barrier(0);
  __builtin_amdgcn_s_barrier();
  __builtin_amdgcn_sched_barrier(0);
}
// single combined wait: vm counted + full lgkm drain (reader AND writer side)
static __device__ __forceinline__ void qkv_wait4() {
  asm volatile("s_waitcnt vmcnt(4) lgkmcnt(0)" ::: "memory");
  __builtin_amdgcn_sched_barrier(0);
  __builtin_amdgcn_s_barrier();
  __builtin_amdgcn_sched_barrier(0);
}
static __device__ __forceinline__ void qkv_wait0() {
  asm volatile("s_waitcnt vmcnt(0) lgkmcnt(0)" ::: "memory");
  __builtin_amdgcn_sched_barrier(0);
  __builtin_amdgcn_s_barrier();
  __builtin_amdgcn_sched_barrier(0);
}

// ---------------- 4x W [K][N] f32 -> Wt [N][K] bf16, one dispatch ---------
__global__ void __launch_bounds__(256) transpose4_kernel(const float* __restrict__ Wq,
                                                         const float* __restrict__ Wk,
                                                         const float* __restrict__ Wv,
                                                         const float* __restrict__ Wo,
                                                         u16* __restrict__ Wts) {
  __shared__ float tile[32][33];
  const int z = blockIdx.z;
  const float* W = (z == 0) ? Wq : (z == 1) ? Wk : (z == 2) ? Wv : Wo;
  u16* Wt = Wts + (size_t)z * Dn * Dn;
  const int n0 = blockIdx.x * 32, k0 = blockIdx.y * 32;
  const int tx = threadIdx.x & 31, ty = (threadIdx.x >> 5) * 4;
#pragma unroll
  for (int i = 0; i < 4; ++i)
    tile[ty + i][tx] = W[(size_t)(k0 + ty + i) * Dn + n0 + tx];
  __syncthreads();
#pragma unroll
  for (int i = 0; i < 4; ++i)
    Wt[(size_t)(n0 + ty + i) * Dn + k0 + tx] = f2bf(tile[tx][ty + i]);
}

// ---------------- fused QKV projection GEMM (f32 A, single-barrier) --------
// (unchanged from R11: best-measured f32-fused structure)
__global__ void __launch_bounds__(256) gemm_qkv_kernel(const float* __restrict__ q_in,
                                                       const float* __restrict__ k_in,
                                                       const float* __restrict__ v_in,
                                                       const u16* __restrict__ Wts,
                                                       const float* __restrict__ bq,
                                                       const float* __restrict__ bk,
                                                       const float* __restrict__ bv,
                                                       u16* __restrict__ outbase) {
  __shared__ u16 As[2][128 * 64];
  __shared__ u16 Bs[3][128 * 64];

  const int bid = blockIdx.x;
  const int xcd = bid & 7;
  const int loc = bid >> 3;                 // 0..191
  const int nb = loc & 7;
  const int panel = xcd * 24 + (loc >> 3);  // 0..191
  const int z = panel >> 6;                 // 64 m-panels per tensor
  const int m0 = (panel & 63) * 128, n0 = nb * 128;

  const float* A = (z == 0) ? q_in : (z == 1) ? k_in : v_in;
  const u16* Bt = Wts + (size_t)z * Dn * Dn;
  const float* bias = (z == 0) ? bq : (z == 1) ? bk : bv;
  u16* outp = outbase + (size_t)z * Mn * Dn;
  const float scale = (z == 0) ? 0.125f * 1.4426950408889634f : 1.0f;

  const int tid = threadIdx.x;
  const int wave = tid >> 6, lane = tid & 63;
  const int g = lane >> 4, c = lane & 15;
  const int wm = wave >> 1, wn = wave & 1;
  const int srow = lane >> 3, blk = lane & 7;

  f32x4 acc[4][4] = {};
  constexpr int NK = Dn / 64;  // 16

  f32x4 rA0lo[4], rA0hi[4], rA1lo[4], rA1hi[4];

  auto issueA = [&](int k0, f32x4 (&rlo)[4], f32x4 (&rhi)[4]) {
#pragma unroll
    for (int i = 0; i < 4; ++i) {
      const int row = (wave * 4 + i) * 8 + srow;
      const float* src = A + (size_t)(m0 + row) * Dn + k0 + blk * 8;
      rlo[i] = *(const f32x4*)src;
      rhi[i] = *(const f32x4*)(src + 4);
    }
  };
  auto writeA = [&](u16* dst, f32x4 (&rlo)[4], f32x4 (&rhi)[4]) {
#pragma unroll
    for (int i = 0; i < 4; ++i) {
      const int row = (wave * 4 + i) * 8 + srow;
      u32x4 w;
      w[0] = cvtpk(rlo[i][0], rlo[i][1]);
      w[1] = cvtpk(rlo[i][2], rlo[i][3]);
      w[2] = cvtpk(rhi[i][0], rhi[i][1]);
      w[3] = cvtpk(rhi[i][2], rhi[i][3]);
      *(u32x4*)(dst + row * 64 + ((blk ^ srow) * 8)) = w;
    }
  };
  auto issueB = [&](int k0, u16* dstB) {
#pragma unroll
    for (int i = 0; i < 4; ++i) {
      const int ch = wave * 4 + i, row = ch * 8 + srow, sb = blk ^ srow;
      async16(Bt + (size_t)(n0 + row) * Dn + k0 + sb * 8, dstB + ch * 512);
    }
  };
  auto mfma_tile = [&](const u16* Asb, const u16* Bsb) {
#pragma unroll
    for (int kk = 0; kk < 2; ++kk) {
      bf16x8 af[4], bfr[4];
#pragma unroll
      for (int mi = 0; mi < 4; ++mi)
        af[mi] = *(const bf16x8*)(Asb + (wm * 64 + mi * 16 + c) * 64 +
                                  (((kk * 4 + g) ^ (c & 7)) * 8));
#pragma unroll
      for (int ni = 0; ni < 4; ++ni)
        bfr[ni] = *(const bf16x8*)(Bsb + (wn * 64 + ni * 16 + c) * 64 +
                                   (((kk * 4 + g) ^ (c & 7)) * 8));
      __builtin_amdgcn_s_setprio(1);
#pragma unroll
      for (int mi = 0; mi < 4; ++mi)
#pragma unroll
        for (int ni = 0; ni < 4; ++ni)
          acc[mi][ni] = __builtin_amdgcn_mfma_f32_16x16x32_bf16(af[mi], bfr[ni],
                                                                acc[mi][ni], 0, 0, 0);
      __builtin_amdgcn_s_setprio(0);
    }
  };

  u16 *bA = Bs[0], *bB = Bs[1], *bC = Bs[2];

  issueA(0, rA0lo, rA0hi);
  issueB(0, bA);
  asm volatile("s_waitcnt vmcnt(4)" ::: "memory");
  __builtin_amdgcn_sched_barrier(0);
  writeA(As[0], rA0lo, rA0hi);
  issueA(64, rA1lo, rA1hi);
  issueB(64, bB);

  for (int kp = 0; kp < NK; kp += 2) {
    {  // t = kp (even)
      const int t = kp;
      if (t + 1 < NK) qkv_wait4(); else qkv_wait0();
      if (t + 2 < NK) {
        issueA((t + 2) * 64, rA0lo, rA0hi);
        issueB((t + 2) * 64, bC);
      }
      if (t + 1 < NK) writeA(As[1], rA1lo, rA1hi);
      mfma_tile(As[0], bA);
      u16* tb = bA; bA = bB; bB = bC; bC = tb;
    }
    {  // t = kp+1 (odd)
      const int t = kp + 1;
      if (t + 1 < NK) qkv_wait4(); else qkv_wait0();
      if (t + 2 < NK) {
        issueA((t + 2) * 64, rA1lo, rA1hi);
        issueB((t + 2) * 64, bC);
      }
      if (t + 1 < NK) writeA(As[0], rA0lo, rA0hi);
      mfma_tile(As[1], bA);
      u16* tb = bA; bA = bB; bB = bC; bC = tb;
    }
  }

  const bool vmode = (z == 2);
#pragma unroll
  for (int ni = 0; ni < 4; ++ni) {
    const int col = n0 + wn * 64 + ni * 16 + c;
    const float bv = bias[col];
    const int hh = col >> 6, dh = col & 63;
#pragma unroll
    for (int mi = 0; mi < 4; ++mi) {
      const int row = m0 + wm * 64 + mi * 16 + g * 4;
      const int bb = row >> 11, s = row & 2047;
      if (!vmode) {
        u16* o = outp + (((size_t)(bb * Hn + hh) * Sn + s) * DHn + dh);
#pragma unroll
        for (int r = 0; r < 4; ++r)
          o[(size_t)r * DHn] = f2bf((acc[mi][ni][r] + bv) * scale);
      } else {
        u16x4 pk;
#pragma unroll
        for (int r = 0; r < 4; ++r) pk[r] = f2bf(acc[mi][ni][r] + bv);
        *(u16x4*)(outp + ((size_t)(bb * Hn + hh) * DHn + dh) * Sn + s) = pk;
      }
    }
  }
}

// ---------------- output GEMM: d_out[M,N] f32 = Ob @ Wot^T + bo ------------
// (unchanged from R11)
__global__ void __launch_bounds__(256) gemm_o_kernel(const u16* __restrict__ A,
                                                     const u16* __restrict__ Bt,
                                                     const float* __restrict__ bias,
                                                     float* __restrict__ outp) {
  __shared__ u16 As[2][128 * 64];
  __shared__ u16 Bs[2][128 * 64];
  const int bid = blockIdx.x;
  const int xcd = bid & 7;
  const int loc = bid >> 3;
  const int nb = loc & 7;
  const int panel = xcd * 8 + (loc >> 3);
  const int m0 = panel * 128, n0 = nb * 128;

  const int tid = threadIdx.x;
  const int wave = tid >> 6, lane = tid & 63;
  const int g = lane >> 4, c = lane & 15;
  const int wm = wave >> 1, wn = wave & 1;
  const int srow = lane >> 3, blk = lane & 7;

  f32x4 acc[4][4] = {};
  constexpr int NK = Dn / 64;  // 16

#pragma unroll
  for (int p = 0; p < 2; ++p) {
    const int k0 = p * 64;
#pragma unroll
    for (int i = 0; i < 4; ++i) {
      const int ch = wave * 4 + i;
      const int row = ch * 8 + srow;
      const int sblk = blk ^ srow;
      async16(A + (size_t)(m0 + row) * Dn + k0 + sblk * 8, As[p] + ch * 512);
      async16(Bt + (size_t)(n0 + row) * Dn + k0 + sblk * 8, Bs[p] + ch * 512);
    }
  }

  for (int k = 0; k < NK; ++k) {
    const int cur = k & 1;
    if (k + 1 < NK) wait_bar8(); else wait_bar0();

#pragma unroll
    for (int kk = 0; kk < 2; ++kk) {
      bf16x8 af[4], bfr[4];
#pragma unroll
      for (int mi = 0; mi < 4; ++mi)
        af[mi] = *(const bf16x8*)(As[cur] + (wm * 64 + mi * 16 + c) * 64 +
                                  (((kk * 4 + g) ^ (c & 7)) * 8));
#pragma unroll
      for (int ni = 0; ni < 4; ++ni)
        bfr[ni] = *(const bf16x8*)(Bs[cur] + (wn * 64 + ni * 16 + c) * 64 +
                                   (((kk * 4 + g) ^ (c & 7)) * 8));
#pragma unroll
      for (int mi = 0; mi < 4; ++mi)
#pragma unroll
        for (int ni = 0; ni < 4; ++ni)
          acc[mi][ni] = __builtin_amdgcn_mfma_f32_16x16x32_bf16(af[mi], bfr[ni],
                                                                acc[mi][ni], 0, 0, 0);
    }

    raw_bar();
    if (k + 2 < NK) {
      const int k0 = (k + 2) * 64;
#pragma unroll
      for (int i = 0; i < 4; ++i) {
        const int ch = wave * 4 + i;
        const int row = ch * 8 + srow;
        const int sblk = blk ^ srow;
        async16(A + (size_t)(m0 + row) * Dn + k0 + sblk * 8, As[cur] + ch * 512);
        async16(Bt + (size_t)(n0 + row) * Dn + k0 + sblk * 8, Bs[cur] + ch * 512);
      }
    }
  }

#pragma unroll
  for (int ni = 0; ni < 4; ++ni) {
    const int col = n0 + wn * 64 + ni * 16 + c;
    const float bv = bias[col];
#pragma unroll
    for (int mi = 0; mi < 4; ++mi) {
      const int row = m0 + wm * 64 + mi * 16 + g * 4;
      float* o = outp + (size_t)row * Dn + col;
#pragma unroll
      for (int r = 0; r < 4; ++r) o[(size_t)r * Dn] = acc[mi][ni][r] + bv;
    }
  }
}

// ---------------- flash attention: T15 double-pipeline --------------------
// Iteration t issues QK(t) then PV(t-1) back-to-back on the MFMA pipe, then
// runs softmax(t) on the VALU while the MFMA pipe drains. V is quad-buffered
// (PV reads V one iteration late; slot(t+2)%4 != slot(t-1)%4 keeps the
// prefetch WAR-safe since every ds_read is consumed by an MFMA within its
// iteration). P-fragments ping-pong between two named register sets via a
// 2x-unrolled loop.
__global__ void __launch_bounds__(512, 4) attn_kernel(const u16* __restrict__ Q,
                                                      const u16* __restrict__ Kp,
                                                      const u16* __restrict__ VT,
                                                      u16* __restrict__ O) {
  __shared__ u16 Ks[3][64 * 64];
  __shared__ u16 Vs[4][64 * 64];
  const int tid = threadIdx.x;
  const int wave = tid >> 6, lane = tid & 63;
  const int g = lane >> 4, c = lane & 15;
  const int bh = blockIdx.x;
  const int q0 = blockIdx.y * 256 + wave * 32;
  const u16* Qb = Q + (size_t)bh * Sn * DHn;
  const u16* Kb = Kp + (size_t)bh * Sn * DHn;
  const u16* Vb = VT + (size_t)bh * DHn * Sn;

  bf16x8 qf[2][2];
#pragma unroll
  for (int fq = 0; fq < 2; ++fq)
#pragma unroll
    for (int kk = 0; kk < 2; ++kk)
      qf[fq][kk] = *(const bf16x8*)(Qb + (size_t)(q0 + fq * 16 + c) * DHn + kk * 32 + g * 8);

  f32x4 ot[4][2] = {};
  f32x4 lacc[2] = {};
  u16x8 one8u;
#pragma unroll
  for (int j = 0; j < 8; ++j) one8u[j] = 0x3F80;  // bf16 1.0
  const bf16x8 one8 = __builtin_bit_cast(bf16x8, one8u);
  const f32x4 zf = {};

  const int srow = lane >> 3, blk = lane & 7;
  const int krow = wave * 8 + srow;
  const int sblk = blk ^ srow;
  constexpr int NT = Sn / 64;  // 32

  u16 *kA = Ks[0], *kB = Ks[1], *kC = Ks[2];
  u16 *vP = Vs[3], *vA = Vs[0], *vB = Vs[1], *vC = Vs[2];

  // prologue: stage tiles 0 and 1
#pragma unroll
  for (int tt = 0; tt < 2; ++tt) {
    const int kt = tt * 64;
    async16(Kb + (size_t)(kt + krow) * DHn + sblk * 8, Ks[tt] + wave * 512);
    async16(Vb + (size_t)krow * Sn + kt + sblk * 8, Vs[tt] + wave * 512);
  }

  bf16x8 pfA[2][2] = {}, pfB[2][2] = {};

  auto do_qk = [&](f32x4 (&st)[4][2]) {
    bf16x8 kf[4];
#pragma unroll
    for (int fk = 0; fk < 4; ++fk)
      kf[fk] = *(const bf16x8*)(kA + (fk * 16 + c) * 64 + ((g ^ (c & 7)) * 8));
    __builtin_amdgcn_s_setprio(1);
#pragma unroll
    for (int fk = 0; fk < 4; ++fk)
#pragma unroll
      for (int fq = 0; fq < 2; ++fq)
        st[fk][fq] = __builtin_amdgcn_mfma_f32_16x16x32_bf16(kf[fk], qf[fq][0],
                                                             zf, 0, 0, 0);
    __builtin_amdgcn_s_setprio(0);
#pragma unroll
    for (int fk = 0; fk < 4; ++fk)
      kf[fk] = *(const bf16x8*)(kA + (fk * 16 + c) * 64 + (((4 + g) ^ (c & 7)) * 8));
    __builtin_amdgcn_s_setprio(1);
#pragma unroll
    for (int fk = 0; fk < 4; ++fk)
#pragma unroll
      for (int fq = 0; fq < 2; ++fq)
        st[fk][fq] = __builtin_amdgcn_mfma_f32_16x16x32_bf16(kf[fk], qf[fq][1],
                                                             st[fk][fq], 0, 0, 0);
    __builtin_amdgcn_s_setprio(0);
  };

  auto do_pv = [&](const bf16x8 (&pfv)[2][2]) {
#pragma unroll
    for (int kk = 0; kk < 2; ++kk) {
      bf16x8 vf[4];
#pragma unroll
      for (int fa = 0; fa < 4; ++fa)
        vf[fa] = *(const bf16x8*)(vP + (fa * 16 + c) * 64 +
                                  (((kk * 4 + g) ^ (c & 7)) * 8));
      __builtin_amdgcn_s_setprio(1);
#pragma unroll
      for (int fa = 0; fa < 4; ++fa)
#pragma unroll
        for (int fq = 0; fq < 2; ++fq)
          ot[fa][fq] = __builtin_amdgcn_mfma_f32_16x16x32_bf16(vf[fa], pfv[kk][fq],
                                                               ot[fa][fq], 0, 0, 0);
#pragma unroll
      for (int fq = 0; fq < 2; ++fq)
        lacc[fq] = __builtin_amdgcn_mfma_f32_16x16x32_bf16(one8, pfv[kk][fq],
                                                           lacc[fq], 0, 0, 0);
      __builtin_amdgcn_s_setprio(0);
    }
  };

  auto do_sm = [&](f32x4 (&st)[4][2], bf16x8 (&pfo)[2][2]) {
#pragma unroll
    for (int fq = 0; fq < 2; ++fq)
#pragma unroll
      for (int fk = 0; fk < 4; ++fk)
#pragma unroll
        for (int r = 0; r < 4; ++r)
          st[fk][fq][r] = __builtin_amdgcn_exp2f(st[fk][fq][r]);
#pragma unroll
    for (int fq = 0; fq < 2; ++fq)
#pragma unroll
      for (int kk = 0; kk < 2; ++kk) {
        u32x4 pw;
#pragma unroll
        for (int w = 0; w < 2; ++w) {
          const u32 a = cvtpk(st[2 * kk][fq][2 * w], st[2 * kk][fq][2 * w + 1]);
          const u32 b = cvtpk(st[2 * kk + 1][fq][2 * w], st[2 * kk + 1][fq][2 * w + 1]);
          const u32x2 p1 = __builtin_amdgcn_permlane32_swap(a, b, false, false);
          const u32x2 p2 = __builtin_amdgcn_permlane16_swap(p1[0], p1[1], false, false);
          pw[w] = p2[0];
          pw[2 + w] = p2[1];
        }
        pfo[kk][fq] = __builtin_bit_cast(bf16x8, pw);
      }
  };

  auto rotate = [&]() {
    u16* tk = kA; kA = kB; kB = kC; kC = tk;
    u16* tv = vP; vP = vA; vA = vB; vB = vC; vC = tv;
  };

  auto body = [&](int t, const bf16x8 (&pfIn)[2][2], bf16x8 (&pfOut)[2][2],
                  bool doPV) {
    if (t + 1 < NT) wait_bar2(); else wait_bar0();
    if (t + 2 < NT) {
      const int kt = (t + 2) * 64;
      async16(Kb + (size_t)(kt + krow) * DHn + sblk * 8, kC + wave * 512);
      async16(Vb + (size_t)krow * Sn + kt + sblk * 8, vC + wave * 512);
    }
    f32x4 st[4][2];
    do_qk(st);
    if (doPV) do_pv(pfIn);
    do_sm(st, pfOut);
    rotate();
  };

  body(0, pfB, pfA, false);
  for (int tp = 1; tp < NT; tp += 2) {
    body(tp, pfA, pfB, true);
    if (tp + 1 < NT) body(tp + 1, pfB, pfA, true);
  }
  do_pv(pfB);  // P(NT-1); vP = slot(NT-1) after final rotate

  const int bb = bh >> 4, hh = bh & 15;
#pragma unroll
  for (int fq = 0; fq < 2; ++fq) {
    const float inv = 1.f / lacc[fq][0];
    const int s = q0 + fq * 16 + c;
#pragma unroll
    for (int fa = 0; fa < 4; ++fa) {
      const int dh = fa * 16 + g * 4;
      u16x4 pk;
#pragma unroll
      for (int r = 0; r < 4; ++r) pk[r] = f2bf(ot[fa][fq][r] * inv);
      *(u16x4*)(O + ((size_t)bb * Sn + s) * Dn + hh * 64 + dh) = pk;
    }
  }
}

// ---------------- launch ----------------
extern "C" void kernel_launch(void* const* d_in, const int* in_sizes, int n_in,
                              void* d_out, int out_size, void* d_ws, size_t ws_size,
                              hipStream_t stream) {
  (void)in_sizes; (void)n_in; (void)out_size; (void)ws_size;
  const float* q_in = (const float*)d_in[0];
  const float* k_in = (const float*)d_in[1];
  const float* v_in = (const float*)d_in[2];
  const float* Wq = (const float*)d_in[3];
  const float* bq = (const float*)d_in[4];
  const float* Wk = (const float*)d_in[5];
  const float* bk = (const float*)d_in[6];
  const float* Wv = (const float*)d_in[7];
  const float* bv = (const float*)d_in[8];
  const float* Wo = (const float*)d_in[9];
  const float* bo = (const float*)d_in[10];

  char* ws = (char*)d_ws;
  const size_t szX = (size_t)Mn * Dn * 2;  // 16 MiB
  const size_t szW = (size_t)Dn * Dn * 2;  // 2 MiB
  u16* Wts = (u16*)ws;                       // Wqt|Wkt|Wvt|Wot contiguous
  u16* Qb = (u16*)(ws + 4 * szW + 0 * szX);  // Qb|Kb|VTb contiguous
  u16* Kb = (u16*)(ws + 4 * szW + 1 * szX);
  u16* VTb = (u16*)(ws + 4 * szW + 2 * szX);
  u16* Ob = (u16*)(ws + 4 * szW + 3 * szX);
  // total: 4*2 + 4*16 = 72 MiB of workspace

  transpose4_kernel<<<dim3(32, 32, 4), 256, 0, stream>>>(Wq, Wk, Wv, Wo, Wts);

  gemm_qkv_kernel<<<1536, 256, 0, stream>>>(q_in, k_in, v_in, Wts, bq, bk, bv, Qb);

  attn_kernel<<<dim3(Bn * Hn, Sn / 256), 512, 0, stream>>>(Qb, Kb, VTb, Ob);

  gemm_o_kernel<<<512, 256, 0, stream>>>(Ob, Wts + (size_t)3 * Dn * Dn, bo,
                                         (float*)d_out);
}

// Round 14
// 172.736 us; speedup vs baseline: 1.1232x; 1.1232x over previous
//
#include <hip/hip_runtime.h>

typedef float f32x4 __attribute__((ext_vector_type(4)));
typedef __bf16 bf16x8 __attribute__((ext_vector_type(8)));
typedef unsigned short u16;
typedef unsigned int u32;
typedef u16 u16x4 __attribute__((ext_vector_type(4)));
typedef u16 u16x8 __attribute__((ext_vector_type(8)));
typedef u32 u32x2 __attribute__((ext_vector_type(2)));
typedef u32 u32x4 __attribute__((ext_vector_type(4)));

constexpr int Bn = 4, Sn = 2048, Dn = 1024, Hn = 16, DHn = 64;
constexpr int Mn = Bn * Sn; // 8192

static __device__ __forceinline__ u16 f2bf(float f) {
  return __builtin_bit_cast(u16, (__bf16)f);
}

static __device__ __forceinline__ u32 cvtpk(float lo, float hi) {
  u32 r;
  asm("v_cvt_pk_bf16_f32 %0, %1, %2" : "=v"(r) : "v"(lo), "v"(hi));
  return r;
}

// async global->LDS, 16B per lane. LDS dest is wave-uniform base + lane*16.
static __device__ __forceinline__ void async16(const void* g, void* l) {
  __builtin_amdgcn_global_load_lds((const __attribute__((address_space(1))) u32*)g,
                                   (__attribute__((address_space(3))) u32*)l, 16, 0, 0);
}

// counted vmcnt wait + raw barrier, fenced (guide rule #18)
static __device__ __forceinline__ void wait_bar2() {
  asm volatile("s_waitcnt vmcnt(2)" ::: "memory");
  __builtin_amdgcn_sched_barrier(0);
  __builtin_amdgcn_s_barrier();
  __builtin_amdgcn_sched_barrier(0);
}
static __device__ __forceinline__ void wait_bar8() {
  asm volatile("s_waitcnt vmcnt(8)" ::: "memory");
  __builtin_amdgcn_sched_barrier(0);
  __builtin_amdgcn_s_barrier();
  __builtin_amdgcn_sched_barrier(0);
}
static __device__ __forceinline__ void wait_bar0() {
  asm volatile("s_waitcnt vmcnt(0)" ::: "memory");
  __builtin_amdgcn_sched_barrier(0);
  __builtin_amdgcn_s_barrier();
  __builtin_amdgcn_sched_barrier(0);
}
static __device__ __forceinline__ void raw_bar() {
  __builtin_amdgcn_sched_barrier(0);
  __builtin_amdgcn_s_barrier();
  __builtin_amdgcn_sched_barrier(0);
}
// single combined wait: vm counted + full lgkm drain (reader AND writer side)
static __device__ __forceinline__ void qkv_wait2() {
  asm volatile("s_waitcnt vmcnt(2) lgkmcnt(0)" ::: "memory");
  __builtin_amdgcn_sched_barrier(0);
  __builtin_amdgcn_s_barrier();
  __builtin_amdgcn_sched_barrier(0);
}
static __device__ __forceinline__ void qkv_wait0() {
  asm volatile("s_waitcnt vmcnt(0) lgkmcnt(0)" ::: "memory");
  __builtin_amdgcn_sched_barrier(0);
  __builtin_amdgcn_s_barrier();
  __builtin_amdgcn_sched_barrier(0);
}

// ---------------- 4x W [K][N] f32 -> Wt [N][K] bf16, one dispatch ---------
__global__ void __launch_bounds__(256) transpose4_kernel(const float* __restrict__ Wq,
                                                         const float* __restrict__ Wk,
                                                         const float* __restrict__ Wv,
                                                         const float* __restrict__ Wo,
                                                         u16* __restrict__ Wts) {
  __shared__ float tile[32][33];
  const int z = blockIdx.z;
  const float* W = (z == 0) ? Wq : (z == 1) ? Wk : (z == 2) ? Wv : Wo;
  u16* Wt = Wts + (size_t)z * Dn * Dn;
  const int n0 = blockIdx.x * 32, k0 = blockIdx.y * 32;
  const int tx = threadIdx.x & 31, ty = (threadIdx.x >> 5) * 4;
#pragma unroll
  for (int i = 0; i < 4; ++i)
    tile[ty + i][tx] = W[(size_t)(k0 + ty + i) * Dn + n0 + tx];
  __syncthreads();
#pragma unroll
  for (int i = 0; i < 4; ++i)
    Wt[(size_t)(n0 + ty + i) * Dn + k0 + tx] = f2bf(tile[tx][ty + i]);
}

// ---------------- fused QKV projection GEMM (f32 A, 8 waves, 1 barrier) ----
// C[M,N] = A_f32[M,K] @ Wt[N,K]^T + bias, A converted to bf16 in-pipeline.
// R11's single-barrier schedule widened to 8 waves (R5 precedent: doubles
// waves/SIMD 2->4 at the same 2 blocks/CU, attacking the latency-bound
// symptom). Per wave per tile: 2 A-chunks (4 f32x4 loads), 2 B-chunks
// (async16), 16 MFMA into acc[4][2] (64x32 output). vmcnt ledger at top of
// tile t: [B(t)x2, A(t+1)x4, B(t+1)x2] -> vmcnt(2) lgkmcnt(0); vmcnt(0) only
// on the last tile. XCD decode keeps an A-panel's 8 N-blocks on one XCD.
__global__ void __launch_bounds__(512, 4) gemm_qkv_kernel(const float* __restrict__ q_in,
                                                          const float* __restrict__ k_in,
                                                          const float* __restrict__ v_in,
                                                          const u16* __restrict__ Wts,
                                                          const float* __restrict__ bq,
                                                          const float* __restrict__ bk,
                                                          const float* __restrict__ bv,
                                                          u16* __restrict__ outbase) {
  __shared__ u16 As[2][128 * 64];
  __shared__ u16 Bs[3][128 * 64];

  const int bid = blockIdx.x;
  const int xcd = bid & 7;
  const int loc = bid >> 3;                 // 0..191
  const int nb = loc & 7;
  const int panel = xcd * 24 + (loc >> 3);  // 0..191
  const int z = panel >> 6;                 // 64 m-panels per tensor
  const int m0 = (panel & 63) * 128, n0 = nb * 128;

  const float* A = (z == 0) ? q_in : (z == 1) ? k_in : v_in;
  const u16* Bt = Wts + (size_t)z * Dn * Dn;
  const float* bias = (z == 0) ? bq : (z == 1) ? bk : bv;
  u16* outp = outbase + (size_t)z * Mn * Dn;
  const float scale = (z == 0) ? 0.125f * 1.4426950408889634f : 1.0f;

  const int tid = threadIdx.x;
  const int wave = tid >> 6, lane = tid & 63;
  const int g = lane >> 4, c = lane & 15;
  const int wm = wave >> 2, wn = wave & 3;  // 2m x 4n of 64x32
  const int srow = lane >> 3, blk = lane & 7;

  f32x4 acc[4][2] = {};
  constexpr int NK = Dn / 64;  // 16

  // two A-staging register sets, selected by compile-time parity
  f32x4 rA0lo[2], rA0hi[2], rA1lo[2], rA1hi[2];

  auto issueA = [&](int k0, f32x4 (&rlo)[2], f32x4 (&rhi)[2]) {
#pragma unroll
    for (int i = 0; i < 2; ++i) {
      const int row = (wave * 2 + i) * 8 + srow;
      const float* src = A + (size_t)(m0 + row) * Dn + k0 + blk * 8;
      rlo[i] = *(const f32x4*)src;
      rhi[i] = *(const f32x4*)(src + 4);
    }
  };
  auto writeA = [&](u16* dst, f32x4 (&rlo)[2], f32x4 (&rhi)[2]) {
#pragma unroll
    for (int i = 0; i < 2; ++i) {
      const int row = (wave * 2 + i) * 8 + srow;
      u32x4 w;
      w[0] = cvtpk(rlo[i][0], rlo[i][1]);
      w[1] = cvtpk(rlo[i][2], rlo[i][3]);
      w[2] = cvtpk(rhi[i][0], rhi[i][1]);
      w[3] = cvtpk(rhi[i][2], rhi[i][3]);
      *(u32x4*)(dst + row * 64 + ((blk ^ srow) * 8)) = w;
    }
  };
  auto issueB = [&](int k0, u16* dstB) {
#pragma unroll
    for (int i = 0; i < 2; ++i) {
      const int ch = wave * 2 + i, row = ch * 8 + srow, sb = blk ^ srow;
      async16(Bt + (size_t)(n0 + row) * Dn + k0 + sb * 8, dstB + ch * 512);
    }
  };
  auto mfma_tile = [&](const u16* Asb, const u16* Bsb) {
#pragma unroll
    for (int kk = 0; kk < 2; ++kk) {
      bf16x8 af[4], bfr[2];
#pragma unroll
      for (int mi = 0; mi < 4; ++mi)
        af[mi] = *(const bf16x8*)(Asb + (wm * 64 + mi * 16 + c) * 64 +
                                  (((kk * 4 + g) ^ (c & 7)) * 8));
#pragma unroll
      for (int ni = 0; ni < 2; ++ni)
        bfr[ni] = *(const bf16x8*)(Bsb + (wn * 32 + ni * 16 + c) * 64 +
                                   (((kk * 4 + g) ^ (c & 7)) * 8));
      __builtin_amdgcn_s_setprio(1);
#pragma unroll
      for (int mi = 0; mi < 4; ++mi)
#pragma unroll
        for (int ni = 0; ni < 2; ++ni)
          acc[mi][ni] = __builtin_amdgcn_mfma_f32_16x16x32_bf16(af[mi], bfr[ni],
                                                                acc[mi][ni], 0, 0, 0);
      __builtin_amdgcn_s_setprio(0);
    }
  };

  u16 *bA = Bs[0], *bB = Bs[1], *bC = Bs[2];

  // prologue: A(0)->set0, B(0)->bA; wait A(0); stage As[0]; A(1)->set1, B(1)->bB
  issueA(0, rA0lo, rA0hi);
  issueB(0, bA);
  asm volatile("s_waitcnt vmcnt(2)" ::: "memory");   // A(0) landed, B(0) flying
  __builtin_amdgcn_sched_barrier(0);
  writeA(As[0], rA0lo, rA0hi);
  issueA(64, rA1lo, rA1hi);
  issueB(64, bB);
  // in flight: B(0)x2, A(1)x4, B(1)x2 = 8; As[0] ds_writes pending in lgkm

  for (int kp = 0; kp < NK; kp += 2) {
    {  // ---- t = kp (even): read As[0]/bA; write As[1]<-set1; issue t+2->set0,bC
      const int t = kp;
      if (t + 1 < NK) qkv_wait2(); else qkv_wait0();
      if (t + 2 < NK) {
        issueA((t + 2) * 64, rA0lo, rA0hi);
        issueB((t + 2) * 64, bC);
      }
      if (t + 1 < NK) writeA(As[1], rA1lo, rA1hi);
      mfma_tile(As[0], bA);
      u16* tb = bA; bA = bB; bB = bC; bC = tb;
    }
    {  // ---- t = kp+1 (odd): read As[1]/bA; write As[0]<-set0; issue t+2->set1,bC
      const int t = kp + 1;
      if (t + 1 < NK) qkv_wait2(); else qkv_wait0();
      if (t + 2 < NK) {
        issueA((t + 2) * 64, rA1lo, rA1hi);
        issueB((t + 2) * 64, bC);
      }
      if (t + 1 < NK) writeA(As[0], rA0lo, rA0hi);
      mfma_tile(As[1], bA);
      u16* tb = bA; bA = bB; bB = bC; bC = tb;
    }
  }

  // epilogue
  const bool vmode = (z == 2);
#pragma unroll
  for (int ni = 0; ni < 2; ++ni) {
    const int col = n0 + wn * 32 + ni * 16 + c;
    const float bv = bias[col];
    const int hh = col >> 6, dh = col & 63;
#pragma unroll
    for (int mi = 0; mi < 4; ++mi) {
      const int row = m0 + wm * 64 + mi * 16 + g * 4;
      const int bb = row >> 11, s = row & 2047;
      if (!vmode) {
        u16* o = outp + (((size_t)(bb * Hn + hh) * Sn + s) * DHn + dh);
#pragma unroll
        for (int r = 0; r < 4; ++r)
          o[(size_t)r * DHn] = f2bf((acc[mi][ni][r] + bv) * scale);
      } else {
        u16x4 pk;
#pragma unroll
        for (int r = 0; r < 4; ++r) pk[r] = f2bf(acc[mi][ni][r] + bv);
        *(u16x4*)(outp + ((size_t)(bb * Hn + hh) * DHn + dh) * Sn + s) = pk;
      }
    }
  }
}

// ---------------- output GEMM: d_out[M,N] f32 = Ob @ Wot^T + bo ------------
// (unchanged from R11)
__global__ void __launch_bounds__(256) gemm_o_kernel(const u16* __restrict__ A,
                                                     const u16* __restrict__ Bt,
                                                     const float* __restrict__ bias,
                                                     float* __restrict__ outp) {
  __shared__ u16 As[2][128 * 64];
  __shared__ u16 Bs[2][128 * 64];
  const int bid = blockIdx.x;
  const int xcd = bid & 7;
  const int loc = bid >> 3;
  const int nb = loc & 7;
  const int panel = xcd * 8 + (loc >> 3);
  const int m0 = panel * 128, n0 = nb * 128;

  const int tid = threadIdx.x;
  const int wave = tid >> 6, lane = tid & 63;
  const int g = lane >> 4, c = lane & 15;
  const int wm = wave >> 1, wn = wave & 1;
  const int srow = lane >> 3, blk = lane & 7;

  f32x4 acc[4][4] = {};
  constexpr int NK = Dn / 64;  // 16

#pragma unroll
  for (int p = 0; p < 2; ++p) {
    const int k0 = p * 64;
#pragma unroll
    for (int i = 0; i < 4; ++i) {
      const int ch = wave * 4 + i;
      const int row = ch * 8 + srow;
      const int sblk = blk ^ srow;
      async16(A + (size_t)(m0 + row) * Dn + k0 + sblk * 8, As[p] + ch * 512);
      async16(Bt + (size_t)(n0 + row) * Dn + k0 + sblk * 8, Bs[p] + ch * 512);
    }
  }

  for (int k = 0; k < NK; ++k) {
    const int cur = k & 1;
    if (k + 1 < NK) wait_bar8(); else wait_bar0();

#pragma unroll
    for (int kk = 0; kk < 2; ++kk) {
      bf16x8 af[4], bfr[4];
#pragma unroll
      for (int mi = 0; mi < 4; ++mi)
        af[mi] = *(const bf16x8*)(As[cur] + (wm * 64 + mi * 16 + c) * 64 +
                                  (((kk * 4 + g) ^ (c & 7)) * 8));
#pragma unroll
      for (int ni = 0; ni < 4; ++ni)
        bfr[ni] = *(const bf16x8*)(Bs[cur] + (wn * 64 + ni * 16 + c) * 64 +
                                   (((kk * 4 + g) ^ (c & 7)) * 8));
#pragma unroll
      for (int mi = 0; mi < 4; ++mi)
#pragma unroll
        for (int ni = 0; ni < 4; ++ni)
          acc[mi][ni] = __builtin_amdgcn_mfma_f32_16x16x32_bf16(af[mi], bfr[ni],
                                                                acc[mi][ni], 0, 0, 0);
    }

    raw_bar();
    if (k + 2 < NK) {
      const int k0 = (k + 2) * 64;
#pragma unroll
      for (int i = 0; i < 4; ++i) {
        const int ch = wave * 4 + i;
        const int row = ch * 8 + srow;
        const int sblk = blk ^ srow;
        async16(A + (size_t)(m0 + row) * Dn + k0 + sblk * 8, As[cur] + ch * 512);
        async16(Bt + (size_t)(n0 + row) * Dn + k0 + sblk * 8, Bs[cur] + ch * 512);
      }
    }
  }

#pragma unroll
  for (int ni = 0; ni < 4; ++ni) {
    const int col = n0 + wn * 64 + ni * 16 + c;
    const float bv = bias[col];
#pragma unroll
    for (int mi = 0; mi < 4; ++mi) {
      const int row = m0 + wm * 64 + mi * 16 + g * 4;
      float* o = outp + (size_t)row * Dn + col;
#pragma unroll
      for (int r = 0; r < 4; ++r) o[(size_t)r * Dn] = acc[mi][ni][r] + bv;
    }
  }
}

// ---------------- flash attention: 8 waves, triple-buffer, 1 barrier/tile --
// (reverted to R11's proven version)
__global__ void __launch_bounds__(512, 4) attn_kernel(const u16* __restrict__ Q,
                                                      const u16* __restrict__ Kp,
                                                      const u16* __restrict__ VT,
                                                      u16* __restrict__ O) {
  __shared__ u16 Ks[3][64 * 64];
  __shared__ u16 Vs[3][64 * 64];
  const int tid = threadIdx.x;
  const int wave = tid >> 6, lane = tid & 63;
  const int g = lane >> 4, c = lane & 15;
  const int bh = blockIdx.x;
  const int q0 = blockIdx.y * 256 + wave * 32;
  const u16* Qb = Q + (size_t)bh * Sn * DHn;
  const u16* Kb = Kp + (size_t)bh * Sn * DHn;
  const u16* Vb = VT + (size_t)bh * DHn * Sn;

  bf16x8 qf[2][2];
#pragma unroll
  for (int fq = 0; fq < 2; ++fq)
#pragma unroll
    for (int kk = 0; kk < 2; ++kk)
      qf[fq][kk] = *(const bf16x8*)(Qb + (size_t)(q0 + fq * 16 + c) * DHn + kk * 32 + g * 8);

  f32x4 ot[4][2] = {};
  f32x4 lacc[2] = {};
  u16x8 one8u;
#pragma unroll
  for (int j = 0; j < 8; ++j) one8u[j] = 0x3F80;  // bf16 1.0
  const bf16x8 one8 = __builtin_bit_cast(bf16x8, one8u);
  const f32x4 zf = {};

  const int srow = lane >> 3, blk = lane & 7;
  const int krow = wave * 8 + srow;
  const int sblk = blk ^ srow;
  constexpr int NT = Sn / 64;  // 32

  u16 *kA = Ks[0], *kB = Ks[1], *kC = Ks[2];
  u16 *vA = Vs[0], *vB = Vs[1], *vC = Vs[2];

#pragma unroll
  for (int tt = 0; tt < 2; ++tt) {
    const int kt = tt * 64;
    async16(Kb + (size_t)(kt + krow) * DHn + sblk * 8, Ks[tt] + wave * 512);
    async16(Vb + (size_t)krow * Sn + kt + sblk * 8, Vs[tt] + wave * 512);
  }

  for (int t = 0; t < NT; ++t) {
    if (t + 1 < NT) wait_bar2(); else wait_bar0();

    if (t + 2 < NT) {
      const int kt = (t + 2) * 64;
      async16(Kb + (size_t)(kt + krow) * DHn + sblk * 8, kC + wave * 512);
      async16(Vb + (size_t)krow * Sn + kt + sblk * 8, vC + wave * 512);
    }

    f32x4 st[4][2];
    {
      bf16x8 kf[4];
#pragma unroll
      for (int fk = 0; fk < 4; ++fk)
        kf[fk] = *(const bf16x8*)(kA + (fk * 16 + c) * 64 + ((g ^ (c & 7)) * 8));
      __builtin_amdgcn_s_setprio(1);
#pragma unroll
      for (int fk = 0; fk < 4; ++fk)
#pragma unroll
        for (int fq = 0; fq < 2; ++fq)
          st[fk][fq] = __builtin_amdgcn_mfma_f32_16x16x32_bf16(kf[fk], qf[fq][0],
                                                               zf, 0, 0, 0);
      __builtin_amdgcn_s_setprio(0);
#pragma unroll
      for (int fk = 0; fk < 4; ++fk)
        kf[fk] = *(const bf16x8*)(kA + (fk * 16 + c) * 64 + (((4 + g) ^ (c & 7)) * 8));
      __builtin_amdgcn_s_setprio(1);
#pragma unroll
      for (int fk = 0; fk < 4; ++fk)
#pragma unroll
        for (int fq = 0; fq < 2; ++fq)
          st[fk][fq] = __builtin_amdgcn_mfma_f32_16x16x32_bf16(kf[fk], qf[fq][1],
                                                               st[fk][fq], 0, 0, 0);
      __builtin_amdgcn_s_setprio(0);
    }

#pragma unroll
    for (int fq = 0; fq < 2; ++fq)
#pragma unroll
      for (int fk = 0; fk < 4; ++fk)
#pragma unroll
        for (int r = 0; r < 4; ++r)
          st[fk][fq][r] = __builtin_amdgcn_exp2f(st[fk][fq][r]);

    bf16x8 pf[2][2];
#pragma unroll
    for (int fq = 0; fq < 2; ++fq)
#pragma unroll
      for (int kk = 0; kk < 2; ++kk) {
        u32x4 pw;
#pragma unroll
        for (int w = 0; w < 2; ++w) {
          const u32 a = cvtpk(st[2 * kk][fq][2 * w], st[2 * kk][fq][2 * w + 1]);
          const u32 b = cvtpk(st[2 * kk + 1][fq][2 * w], st[2 * kk + 1][fq][2 * w + 1]);
          const u32x2 p1 = __builtin_amdgcn_permlane32_swap(a, b, false, false);
          const u32x2 p2 = __builtin_amdgcn_permlane16_swap(p1[0], p1[1], false, false);
          pw[w] = p2[0];
          pw[2 + w] = p2[1];
        }
        pf[kk][fq] = __builtin_bit_cast(bf16x8, pw);
      }

#pragma unroll
    for (int kk = 0; kk < 2; ++kk) {
      bf16x8 vf[4];
#pragma unroll
      for (int fa = 0; fa < 4; ++fa)
        vf[fa] = *(const bf16x8*)(vA + (fa * 16 + c) * 64 +
                                  (((kk * 4 + g) ^ (c & 7)) * 8));
      __builtin_amdgcn_s_setprio(1);
#pragma unroll
      for (int fa = 0; fa < 4; ++fa)
#pragma unroll
        for (int fq = 0; fq < 2; ++fq)
          ot[fa][fq] = __builtin_amdgcn_mfma_f32_16x16x32_bf16(vf[fa], pf[kk][fq],
                                                               ot[fa][fq], 0, 0, 0);
#pragma unroll
      for (int fq = 0; fq < 2; ++fq)
        lacc[fq] = __builtin_amdgcn_mfma_f32_16x16x32_bf16(one8, pf[kk][fq],
                                                           lacc[fq], 0, 0, 0);
      __builtin_amdgcn_s_setprio(0);
    }

    u16* tk = kA; kA = kB; kB = kC; kC = tk;
    u16* tv = vA; vA = vB; vB = vC; vC = tv;
  }

  const int bb = bh >> 4, hh = bh & 15;
#pragma unroll
  for (int fq = 0; fq < 2; ++fq) {
    const float inv = 1.f / lacc[fq][0];
    const int s = q0 + fq * 16 + c;
#pragma unroll
    for (int fa = 0; fa < 4; ++fa) {
      const int dh = fa * 16 + g * 4;
      u16x4 pk;
#pragma unroll
      for (int r = 0; r < 4; ++r) pk[r] = f2bf(ot[fa][fq][r] * inv);
      *(u16x4*)(O + ((size_t)bb * Sn + s) * Dn + hh * 64 + dh) = pk;
    }
  }
}

// ---------------- launch ----------------
extern "C" void kernel_launch(void* const* d_in, const int* in_sizes, int n_in,
                              void* d_out, int out_size, void* d_ws, size_t ws_size,
                              hipStream_t stream) {
  (void)in_sizes; (void)n_in; (void)out_size; (void)ws_size;
  const float* q_in = (const float*)d_in[0];
  const float* k_in = (const float*)d_in[1];
  const float* v_in = (const float*)d_in[2];
  const float* Wq = (const float*)d_in[3];
  const float* bq = (const float*)d_in[4];
  const float* Wk = (const float*)d_in[5];
  const float* bk = (const float*)d_in[6];
  const float* Wv = (const float*)d_in[7];
  const float* bv = (const float*)d_in[8];
  const float* Wo = (const float*)d_in[9];
  const float* bo = (const float*)d_in[10];

  char* ws = (char*)d_ws;
  const size_t szX = (size_t)Mn * Dn * 2;  // 16 MiB
  const size_t szW = (size_t)Dn * Dn * 2;  // 2 MiB
  u16* Wts = (u16*)ws;                       // Wqt|Wkt|Wvt|Wot contiguous
  u16* Qb = (u16*)(ws + 4 * szW + 0 * szX);  // Qb|Kb|VTb contiguous
  u16* Kb = (u16*)(ws + 4 * szW + 1 * szX);
  u16* VTb = (u16*)(ws + 4 * szW + 2 * szX);
  u16* Ob = (u16*)(ws + 4 * szW + 3 * szX);
  // total: 4*2 + 4*16 = 72 MiB of workspace

  transpose4_kernel<<<dim3(32, 32, 4), 256, 0, stream>>>(Wq, Wk, Wv, Wo, Wts);

  gemm_qkv_kernel<<<1536, 512, 0, stream>>>(q_in, k_in, v_in, Wts, bq, bk, bv, Qb);

  attn_kernel<<<dim3(Bn * Hn, Sn / 256), 512, 0, stream>>>(Qb, Kb, VTb, Ob);

  gemm_o_kernel<<<512, 256, 0, stream>>>(Ob, Wts + (size_t)3 * Dn * Dn, bo,
                                         (float*)d_out);
}